// Round 5
// baseline (185.722 us; speedup 1.0000x reference)
//
#include <hip/hip_runtime.h>
#include <stdint.h>

// Problem constants (match reference file).
constexpr int V    = 200000;
constexpr int F    = 128;
constexpr int KIN  = 64;
constexpr int KSEL = 16;
constexpr int VSEL = 50000;
constexpr int CAP  = 40;   // inverse-map capacity per vertex; Poisson(4) => P(>40) ~ 1e-24

typedef float f32x2 __attribute__((ext_vector_type(2)));
typedef float f32x4 __attribute__((ext_vector_type(4)));

// ---------------- Pass 0: zero the per-vertex ref counts ----------------
__global__ __launch_bounds__(256) void zero_counts_kernel(uint32_t* __restrict__ counts)
{
    const int i = blockIdx.x * 256 + threadIdx.x;
    if (i < V) counts[i] = 0;
}

// ---------------- Pass A: sort neighbors, build inverse map ----------------
// One wave per selected row. Stable top-16 via 64-lane bitonic sort, then
// lanes 0..15 append their (row*16+k) output-slot id to slots[vertex].
// Rows with idx<0 (essentially never) and overflow refs are written directly.
__global__ __launch_bounds__(256) void build_map_kernel(
    const float* __restrict__ distances,
    const int*   __restrict__ nidx,
    const int*   __restrict__ sel_idx,
    const float* __restrict__ features,
    float*       __restrict__ out,
    uint32_t*    __restrict__ counts,
    uint32_t*    __restrict__ slots)
{
    const int lane = threadIdx.x & 63;
    const int wave = threadIdx.x >> 6;
    const int row  = blockIdx.x * 4 + wave;
    if (row >= VSEL) return;

    const int v = sel_idx[row];
    const float d  = distances[(size_t)v * KIN + lane];
    const int   ni = nidx     [(size_t)v * KIN + lane];

    // Stable sort key: fp32 >= 0 keeps bit-pattern order; low 6 bits = column.
    const uint32_t bits = __float_as_uint(ni < 0 ? 1.0e9f : d);
    uint64_t key = ((uint64_t)bits << 6) | (uint32_t)lane;

    #pragma unroll
    for (int k = 2; k <= 64; k <<= 1) {
        #pragma unroll
        for (int j = k >> 1; j >= 1; j >>= 1) {
            const uint64_t other = __shfl_xor(key, j, 64);
            const bool lower    = (lane & j) == 0;
            const bool asc      = (lane & k) == 0;
            const bool take_min = (lower == asc);
            const bool swap     = take_min ? (other < key) : (other > key);
            key = swap ? other : key;
        }
    }

    const int col       = (int)(key & 63);
    const int sorted_ni = __shfl(ni, col, 64);   // lane i (i<16) holds i-th nearest

    // Lanes 0..15 append to the inverse map (one atomic instruction, 16 lanes).
    bool ovf = false;
    if (lane < KSEL && sorted_ni >= 0) {
        const uint32_t slot = atomicAdd(&counts[sorted_ni], 1u);
        if (slot < CAP)
            slots[(size_t)sorted_ni * CAP + slot] = (uint32_t)(row * KSEL + lane);
        else
            ovf = true;
    }

    // Rare paths: zero-fill invalid rows; direct-gather overflow rows.
    const uint64_t zmask = __ballot(lane < KSEL && sorted_ni < 0);
    const uint64_t omask = __ballot(ovf);
    if (zmask | omask) {
        const size_t out_base = (size_t)row * (KSEL * F);
        for (int k = 0; k < KSEL; ++k) {
            const int  idx = __shfl(sorted_ni, k, 64);
            const bool isz = (zmask >> k) & 1ull;
            const bool iso = (omask >> k) & 1ull;
            if (isz) {
                f32x2 z = {0.0f, 0.0f};
                *reinterpret_cast<f32x2*>(&out[out_base + (size_t)k * F + lane * 2]) = z;
            } else if (iso) {
                const f32x2 val = *reinterpret_cast<const f32x2*>(
                                      &features[(size_t)idx * F + lane * 2]);
                *reinterpret_cast<f32x2*>(&out[out_base + (size_t)k * F + lane * 2]) = val;
            }
        }
    }
}

// ---------------- Pass B: stream feature table, scatter to outputs ----------------
// One wave per vertex: sequential 512 B feature-row read (each HBM line read
// exactly once), then c scattered full-line 512 B writes.
__global__ __launch_bounds__(256) void scatter_kernel(
    const float*    __restrict__ features,
    const uint32_t* __restrict__ counts,
    const uint32_t* __restrict__ slots,
    float*          __restrict__ out)
{
    const int lane = threadIdx.x & 63;
    const int wave = threadIdx.x >> 6;
    const int v    = blockIdx.x * 4 + wave;
    if (v >= V) return;

    uint32_t c = counts[v];
    if (c == 0) return;
    c = min(c, (uint32_t)CAP);

    // Lanes 0..c-1 prefetch the output-slot ids in one instruction.
    uint32_t mypos = 0;
    if (lane < (int)c) mypos = slots[(size_t)v * CAP + lane];

    const f32x2 val = *reinterpret_cast<const f32x2*>(&features[(size_t)v * F + lane * 2]);

    for (uint32_t j = 0; j < c; ++j) {
        const uint32_t pos = __shfl(mypos, (int)j, 64);   // row*16+k
        *reinterpret_cast<f32x2*>(&out[(size_t)pos * F + lane * 2]) = val;
    }
}

// ---------------- Legacy fallback (R3 kernel) if ws is too small ----------------
__global__ __launch_bounds__(256) void lcr_gather_kernel(
    const float* __restrict__ features,
    const float* __restrict__ distances,
    const int*   __restrict__ nidx,
    const int*   __restrict__ sel_idx,
    float*       __restrict__ out)
{
    const int lane = threadIdx.x & 63;
    const int wave = threadIdx.x >> 6;
    const int row  = blockIdx.x * 4 + wave;
    if (row >= VSEL) return;

    const int v = sel_idx[row];
    const float d  = distances[(size_t)v * KIN + lane];
    const int   ni = nidx     [(size_t)v * KIN + lane];
    const uint32_t bits = __float_as_uint(ni < 0 ? 1.0e9f : d);
    uint64_t key = ((uint64_t)bits << 6) | (uint32_t)lane;

    #pragma unroll
    for (int k = 2; k <= 64; k <<= 1) {
        #pragma unroll
        for (int j = k >> 1; j >= 1; j >>= 1) {
            const uint64_t other = __shfl_xor(key, j, 64);
            const bool lower    = (lane & j) == 0;
            const bool asc      = (lane & k) == 0;
            const bool take_min = (lower == asc);
            const bool swap     = take_min ? (other < key) : (other > key);
            key = swap ? other : key;
        }
    }

    const int col       = (int)(key & 63);
    const int sorted_ni = __shfl(ni, col, 64);

    const int half = lane >> 5;
    const int l32  = lane & 31;

    int idxs[8];
    #pragma unroll
    for (int p = 0; p < 8; ++p)
        idxs[p] = __shfl(sorted_ni, 2 * p + half, 64);

    f32x4 vals[8];
    #pragma unroll
    for (int p = 0; p < 8; ++p) {
        const int safe = idxs[p] < 0 ? 0 : idxs[p];
        vals[p] = *reinterpret_cast<const f32x4*>(&features[(size_t)safe * F + l32 * 4]);
    }

    const size_t out_base = (size_t)row * (KSEL * F);
    #pragma unroll
    for (int p = 0; p < 8; ++p) {
        f32x4 val = vals[p];
        if (idxs[p] < 0) val = (f32x4)(0.0f);
        __builtin_nontemporal_store(val,
            reinterpret_cast<f32x4*>(&out[out_base + (size_t)(2 * p + half) * F + l32 * 4]));
    }
}

extern "C" void kernel_launch(void* const* d_in, const int* in_sizes, int n_in,
                              void* d_out, int out_size, void* d_ws, size_t ws_size,
                              hipStream_t stream)
{
    const float* features  = (const float*)d_in[0];
    const float* distances = (const float*)d_in[1];
    const int*   nidx      = (const int*)  d_in[2];
    const int*   sel_idx   = (const int*)  d_in[3];
    float* out = (float*)d_out;

    const size_t need = (size_t)V * (1 + CAP) * sizeof(uint32_t);   // ~32.8 MB
    if (ws_size >= need) {
        uint32_t* counts = (uint32_t*)d_ws;
        uint32_t* slots  = counts + V;

        zero_counts_kernel<<<(V + 255) / 256, 256, 0, stream>>>(counts);
        build_map_kernel<<<(VSEL + 3) / 4, 256, 0, stream>>>(
            distances, nidx, sel_idx, features, out, counts, slots);
        scatter_kernel<<<(V + 3) / 4, 256, 0, stream>>>(features, counts, slots, out);
    } else {
        lcr_gather_kernel<<<(VSEL + 3) / 4, 256, 0, stream>>>(
            features, distances, nidx, sel_idx, out);
    }
}